// Round 18
// baseline (479.582 us; speedup 1.0000x reference)
//
#include <hip/hip_runtime.h>
#include <stdint.h>

// ============================================================================
// DistributionLoss: SWD pyramid loss, exact JAX-RNG replication.
// Round 18: round-17 config (best, 452us) + DPP butterflies in swd: xor-1 and
// xor-2 lane exchanges (45% of shuffle ops) via v_mov_b32_dpp quad_perm
// (VALU) instead of ds_bpermute (LDS pipe). Comparator network identical.
// ============================================================================
#define JAX_PARTITIONABLE 1

typedef unsigned int u32;
typedef unsigned short u16;
typedef unsigned long long u64;

#define CAP     512         // max bucket entries in rankfind
#define MAXNB   16384       // max buckets per image (64KB LDS)
#define GRP     16          // hist rows per colscan group
#define SIDX(i) ((i) + ((i) >> 5))   // LDS pad map: +1 word per 32
#define PIDX(i) ((i) + ((i) >> 3))   // swd pad map: +1 word per 8

// ---------------- threefry2x32 (20 rounds), matches jax exactly -------------
__device__ __forceinline__ uint2 tf2(uint2 k, u32 x0, u32 x1) {
  u32 ks0 = k.x, ks1 = k.y, ks2 = k.x ^ k.y ^ 0x1BD11BDAu;
  x0 += ks0; x1 += ks1;
#define TF_RND(R) { x0 += x1; x1 = (x1 << (R)) | (x1 >> (32 - (R))); x1 ^= x0; }
  TF_RND(13) TF_RND(15) TF_RND(26) TF_RND(6)
  x0 += ks1; x1 += ks2 + 1u;
  TF_RND(17) TF_RND(29) TF_RND(16) TF_RND(24)
  x0 += ks2; x1 += ks0 + 2u;
  TF_RND(13) TF_RND(15) TF_RND(26) TF_RND(6)
  x0 += ks0; x1 += ks1 + 3u;
  TF_RND(17) TF_RND(29) TF_RND(16) TF_RND(24)
  x0 += ks1; x1 += ks2 + 4u;
  TF_RND(13) TF_RND(15) TF_RND(26) TF_RND(6)
  x0 += ks2; x1 += ks0 + 5u;
#undef TF_RND
  return make_uint2(x0, x1);
}

__device__ inline void split3(uint2 k, uint2* a, uint2* b, uint2* c) {
#if JAX_PARTITIONABLE
  *a = tf2(k, 0u, 0u); *b = tf2(k, 0u, 1u); *c = tf2(k, 0u, 2u);
#else
  uint2 p0 = tf2(k, 0u, 3u), p1 = tf2(k, 1u, 4u), p2 = tf2(k, 2u, 5u);
  *a = make_uint2(p0.x, p1.x); *b = make_uint2(p2.x, p0.y); *c = make_uint2(p1.y, p2.y);
#endif
}
__device__ inline void split2(uint2 k, uint2* nk, uint2* sub) {
#if JAX_PARTITIONABLE
  *nk = tf2(k, 0u, 0u); *sub = tf2(k, 0u, 1u);
#else
  uint2 p0 = tf2(k, 0u, 2u), p1 = tf2(k, 1u, 3u);
  *nk = make_uint2(p0.x, p1.x); *sub = make_uint2(p0.y, p1.y);
#endif
}
__device__ inline u32 normbits(uint2 kd, u32 idx) {
#if JAX_PARTITIONABLE
  uint2 o = tf2(kd, 0u, idx); return o.x ^ o.y;
#else
  if (idx < 96u) return tf2(kd, idx, idx + 96u).x;
  return tf2(kd, idx - 96u, idx).y;
#endif
}
__device__ inline u32 sortbits(uint2 sk, u32 p, u32 n) {
#if JAX_PARTITIONABLE
  uint2 o = tf2(sk, 0u, p); return o.x ^ o.y;
#else
  u32 h = n >> 1;
  if (p < h) return tf2(sk, p, p + h).x;
  return tf2(sk, p - h, p).y;
#endif
}

// ---------------- erfinv ----------------------------------------------------
__device__ inline double erfinv_d(double x) {
  double w = -log1p(-x * x);
  double p;
  if (w < 5.0) {
    w -= 2.5;
    p = 2.81022636e-08;
    p = 3.43273939e-07 + p * w;
    p = -3.5233877e-06 + p * w;
    p = -4.39150654e-06 + p * w;
    p = 0.00021858087 + p * w;
    p = -0.00125372503 + p * w;
    p = -0.00417768164 + p * w;
    p = 0.246640727 + p * w;
    p = 1.50140941 + p * w;
  } else {
    w = sqrt(w) - 3.0;
    p = -0.000200214257;
    p = 0.000100950558 + p * w;
    p = 0.00134934322 + p * w;
    p = -0.00367342844 + p * w;
    p = 0.00573950773 + p * w;
    p = -0.0076224613 + p * w;
    p = 0.00943887047 + p * w;
    p = 1.00167406 + p * w;
    p = 2.83297682 + p * w;
  }
  double y = p * x;
  for (int it = 0; it < 2; ++it) {
    double e = erf(y) - x;
    y -= e * 0.88622692545275801364 * exp(y * y);
  }
  return y;
}

// ---------------- batched pipeline descriptors ------------------------------
struct Item {
  u32 n, chunk;
  int BB, NB, nblk;
  u32 hm_off;     // u16-element offset into histmat/offT
  u32 gs_off;     // u32-element offset into gsum
  u32 bid_off;    // u16-element offset into barr (bucket-id cache)
  u32 cnt_off;    // u32-element offset into cnt/fbase
  u32 rec_off;    // u32-element offset into rec
  u32 rec_cap;    // total cap (both images); per-image = cap>>1
  u32 blk_start;  // bhist/bscatter grid.x prefix (fine blocks)
  u32 col_start;  // colscan grid.x prefix
  int sub_base;   // keytab index: 8 + lev*6 + (jr-1); +img*3 at runtime
  int first;      // targets are ranks 0..4095 (first round)
  int out_is_idx; // final round -> write idx, else write T
  u32 t_off;      // per-level offset into T/tb/lrarr (lev*8192)
  u32 out_off;    // per-level offset into idx (lev*8192)
};
struct Batch { int nitems; Item it[5]; };

__device__ inline int find_item_blk(const Batch& bt, u32 bx) {
  int it = 0;
  for (int i = 1; i < bt.nitems; i++) if (bx >= bt.it[i].blk_start) it = i;
  return it;
}
__device__ inline int find_item_col(const Batch& bt, u32 bx) {
  int it = 0;
  for (int i = 1; i < bt.nitems; i++) if (bx >= bt.it[i].col_start) it = i;
  return it;
}

// butterfly exchange: DPP for m=1,2 (VALU), bpermute otherwise (m uniform)
__device__ __forceinline__ float bfly(float x, u32 m) {
  if (m == 1u) {
    return __int_as_float(__builtin_amdgcn_mov_dpp(
        __float_as_int(x), 0xB1, 0xF, 0xF, true));   // quad_perm [1,0,3,2]
  } else if (m == 2u) {
    return __int_as_float(__builtin_amdgcn_mov_dpp(
        __float_as_int(x), 0x4E, 0xF, 0xF, true));   // quad_perm [2,3,0,1]
  }
  return __shfl_xor(x, (int)m, 64);
}

// ---------------- kernels ---------------------------------------------------

// keytab: [0..7] kd per level; [8 + lev*6 + img*3 + (r-1)] sort subkeys.
__global__ void __launch_bounds__(512) setup_kernel(uint2* keytab, float* dirs) {
  __shared__ uint2 kt[64];
  if (threadIdx.x == 0) {
    uint2 base = make_uint2(0u, 42u);
    for (int l = 0; l < 8; l++) {
      uint2 kl = tf2(base, 0u, (u32)l);
      uint2 kd, kw, kt3;
      split3(kl, &kd, &kw, &kt3);
      kt[l] = kd;
      if (l >= 3) {
        for (int img = 0; img < 2; img++) {
          uint2 kp = img ? kt3 : kw;
          for (int r = 0; r < 3; r++) {
            uint2 nk, sub;
            split2(kp, &nk, &sub);
            kt[8 + (l - 3) * 6 + img * 3 + r] = sub;
            kp = nk;
          }
        }
      }
    }
  }
  __syncthreads();
  if (threadIdx.x < 38) keytab[threadIdx.x] = kt[threadIdx.x];
  int t = threadIdx.x;  // 512 = 8 levels * 64 dirs
  int l = t >> 6, k = t & 63;
  uint2 kd = kt[l];
  const float lo = -0.9999999403953552f;
  float dv[3];
  for (int c = 0; c < 3; c++) {
    u32 bits = normbits(kd, (u32)(k * 3 + c));
    float f = __uint_as_float((bits >> 9) | 0x3f800000u) - 1.0f;
    float u = f * 2.0f + lo;
    if (u < lo) u = lo;
    dv[c] = 1.4142135f * (float)erfinv_d((double)u);
  }
  float nrm = sqrtf(dv[0] * dv[0] + dv[1] * dv[1] + dv[2] * dv[2]);
  for (int c = 0; c < 3; c++) dirs[l * 192 + k * 3 + c] = dv[c] / nrm;
}

// per-block LDS histogram; also caches each element's bucket id (u16 barr)
__global__ void __launch_bounds__(1024, 8) bhist_kernel(
    u16* histmat, u16* barr, const uint2* keytab, Batch bt) {
  __shared__ u32 lh[MAXNB];
  int item = find_item_blk(bt, blockIdx.x);
  const Item P = bt.it[item];
  int blk = (int)blockIdx.x - (int)P.blk_start;
  int img = blockIdx.y;
  for (int b = threadIdx.x; b < P.NB; b += 1024) lh[b] = 0u;
  __syncthreads();
  uint2 sk = keytab[P.sub_base + img * 3];
  u16* bidp = barr + P.bid_off + (size_t)img * P.n;
  u32 q0 = (u32)blk * P.chunk, q1 = q0 + P.chunk;
  if (q1 > P.n) q1 = P.n;
  for (u32 q = q0 + threadIdx.x; q < q1; q += 1024) {
    u32 b = sortbits(sk, q, P.n) >> (32 - P.BB);
    bidp[q] = (u16)b;
    atomicAdd(&lh[b], 1u);
  }
  __syncthreads();
  u16* row = histmat + P.hm_off + ((size_t)blk * 2 + img) * P.NB;
  for (int b = threadIdx.x; b < P.NB; b += 1024) row[b] = (u16)lh[b];
}

// colscan level 1: per (bucket-range, group) scan GRP hist rows ->
// group-local offT (u16) + group total gsum (u32). grid (cs, GRP-groups).
__global__ void __launch_bounds__(256) bcolscan1_kernel(
    const u16* histmat, u16* offT, u32* gsum, Batch bt) {
  int item = find_item_col(bt, blockIdx.x);
  const Item P = bt.it[item];
  int NB2 = 2 * P.NB;
  int g = blockIdx.y;
  int ngroups = (P.nblk + GRP - 1) / GRP;
  if (g >= ngroups) return;
  int gb = ((int)blockIdx.x - (int)P.col_start) * 256 + threadIdx.x;
  if (gb >= NB2) return;
  int b0 = g * GRP, b1 = b0 + GRP;
  if (b1 > P.nblk) b1 = P.nblk;
  u32 run = 0;
  for (int blk = b0; blk < b1; blk++) {
    size_t ix = P.hm_off + (size_t)blk * NB2 + gb;
    offT[ix] = (u16)run;
    run += histmat[ix];
  }
  gsum[P.gs_off + (size_t)g * NB2 + gb] = run;
}

// colscan level 2: scan gsum across groups in place (-> group bases);
// emit per-bucket totals cnt. grid (cs).
__global__ void __launch_bounds__(256) bcolscan2_kernel(
    u32* gsum, u32* cnt, Batch bt) {
  int item = find_item_col(bt, blockIdx.x);
  const Item P = bt.it[item];
  int NB2 = 2 * P.NB;
  int ngroups = (P.nblk + GRP - 1) / GRP;
  int gb = ((int)blockIdx.x - (int)P.col_start) * 256 + threadIdx.x;
  if (gb >= NB2) return;
  u32 run = 0;
  for (int g = 0; g < ngroups; g++) {
    size_t ix = P.gs_off + (size_t)g * NB2 + gb;
    u32 c = gsum[ix];
    gsum[ix] = run;
    run += c;
  }
  cnt[P.cnt_off + gb] = run;
}

// one block per (item, image): stage cnt->LDS, rank-scan, locate targets,
// flag buckets (bit31), diff-based compact scan -> fbase (per-image rec half)
__global__ void __launch_bounds__(1024) bplan_kernel(
    const u32* cnt, u32* fbase, const u32* Tbuf, u32* tb, u32* lrarr,
    Batch bt) {
  __shared__ u32 sBase[SIDX(MAXNB)];   // 16896 u32 = 66KB (padded)
  __shared__ u32 wsum[16];
  const u32 MASK = 0x7fffffffu;
  const Item P = bt.it[blockIdx.x];
  int img = blockIdx.y;
  int NB = P.NB;
  u32 n = P.n;
  const u32* cntp = cnt + P.cnt_off + (size_t)img * NB;
  u32* fbp = fbase + P.cnt_off + (size_t)img * NB;
  int tid = threadIdx.x;
  int lane = tid & 63, wid = tid >> 6;
  int chunk = (NB + 1023) >> 10;
  int s = tid * chunk, e = s + chunk;
  if (e > NB) e = NB;
  if (s > NB) s = NB;
  for (int i = tid; i < NB; i += 1024) sBase[SIDX(i)] = cntp[i];
  __syncthreads();
  u32 own = 0;
  for (int i = s; i < e; i++) own += sBase[SIDX(i)];
  u32 incl = own;
  #pragma unroll
  for (int d = 1; d < 64; d <<= 1) {
    u32 v = __shfl_up(incl, d, 64);
    if (lane >= d) incl += v;
  }
  if (lane == 63) wsum[wid] = incl;
  __syncthreads();
  if (wid == 0) {
    u32 wv = (lane < 16) ? wsum[lane] : 0u;
    u32 wi = wv;
    #pragma unroll
    for (int d = 1; d < 16; d <<= 1) {
      u32 v = __shfl_up(wi, d, 64);
      if (lane >= d) wi += v;
    }
    if (lane < 16) wsum[lane] = wi - wv;
  }
  __syncthreads();
  u32 run = wsum[wid] + (incl - own);
  for (int i = s; i < e; i++) {
    u32 c = sBase[SIDX(i)];
    sBase[SIDX(i)] = run;
    run += c;
  }
  __syncthreads();
  for (int rl = tid; rl < 4096; rl += 1024) {
    int rg = img * 4096 + rl;
    u32 t = P.first ? (u32)rl : Tbuf[P.t_off + rg];
    int lo = 0, hi = NB - 1;
    while (lo < hi) {
      int mid = (lo + hi + 1) >> 1;
      if ((sBase[SIDX(mid)] & MASK) <= t) lo = mid; else hi = mid - 1;
    }
    tb[P.t_off + rg] = (u32)(img * NB + lo);
    lrarr[P.t_off + rg] = t - (sBase[SIDX(lo)] & MASK);
    atomicOr(&sBase[SIDX(lo)], 0x80000000u);
  }
  __syncthreads();
  // diff-based compact scan (cnt[i] = A[i+1]-A[i]); img-local fbase
  u32 bvA = (e < NB) ? (sBase[SIDX(e)] & MASK) : n;
  u32 vs = 0;
  for (int i = s; i < e; i++) {
    u32 st = sBase[SIDX(i)];
    u32 Ai = st & MASK;
    u32 Ai1 = (i == e - 1) ? bvA : (sBase[SIDX(i + 1)] & MASK);
    vs += (st >> 31) ? (Ai1 - Ai) : 0u;
  }
  u32 vincl = vs;
  #pragma unroll
  for (int d = 1; d < 64; d <<= 1) {
    u32 v = __shfl_up(vincl, d, 64);
    if (lane >= d) vincl += v;
  }
  if (lane == 63) wsum[wid] = vincl;
  __syncthreads();
  if (wid == 0) {
    u32 wv = (lane < 16) ? wsum[lane] : 0u;
    u32 wi = wv;
    #pragma unroll
    for (int d = 1; d < 16; d <<= 1) {
      u32 v = __shfl_up(wi, d, 64);
      if (lane >= d) wi += v;
    }
    if (lane < 16) wsum[lane] = wi - wv;
  }
  __syncthreads();
  u32 run2 = wsum[wid] + (vincl - vs);
  for (int i = s; i < e; i++) {
    u32 st = sBase[SIDX(i)];
    u32 Ai = st & MASK;
    u32 Ai1 = (i == e - 1) ? bvA : (sBase[SIDX(i + 1)] & MASK);
    u32 ci = Ai1 - Ai;
    if (st >> 31) {
      sBase[SIDX(i)] = run2;
      run2 += ci;
    } else {
      sBase[SIDX(i)] = 0xFFFFFFFFu;
    }
  }
  __syncthreads();
  for (int i = tid; i < NB; i += 1024) fbp[i] = sBase[SIDX(i)];
}

// fine-block scatter (XCD-swizzled) reading cached bucket ids from barr.
__global__ void __launch_bounds__(1024, 8) bscatter_kernel(
    u32* rec, const u16* offT, const u32* gsum, const u32* fbase,
    const u16* barr, Batch bt) {
  __shared__ u32 cursor[MAXNB];
  int item = find_item_blk(bt, blockIdx.x);
  const Item P = bt.it[item];
  int il = (int)blockIdx.x - (int)P.blk_start;
  int per = P.nblk >> 3;                 // nblk divisible by 8
  int blk = (il & 7) * per + (il >> 3);  // XCD il&7 gets contiguous chunks
  int img = blockIdx.y;
  int NB2 = 2 * P.NB;
  u32 recbase = P.rec_off + (u32)img * (P.rec_cap >> 1);
  const u16* orow = offT + P.hm_off + (size_t)blk * NB2 + (size_t)img * P.NB;
  const u32* grow = gsum + P.gs_off + (size_t)(blk / GRP) * NB2 + (size_t)img * P.NB;
  const u32* frow = fbase + P.cnt_off + (size_t)img * P.NB;
  for (int b = threadIdx.x; b < P.NB; b += 1024) {
    u32 fb = frow[b];
    cursor[b] = (fb == 0xFFFFFFFFu) ? 0xFFFFFFFFu
                                    : recbase + fb + grow[b] + orow[b];
  }
  __syncthreads();
  const u16* bidp = barr + P.bid_off + (size_t)img * P.n;
  u32 limit = recbase + (P.rec_cap >> 1);
  u32 q0 = (u32)blk * P.chunk, q1 = q0 + P.chunk;
  if (q1 > P.n) q1 = P.n;
  for (u32 q = q0 + threadIdx.x; q < q1; q += 1024) {
    u32 b = (u32)bidp[q];
    if (cursor[b] != 0xFFFFFFFFu) {
      u32 slot = atomicAdd(&cursor[b], 1u);
      if (slot < limit) rec[slot] = q;
    }
  }
}

// wave-per-target rank find: recompute bits from q; 64-bin sub-radix; shfl scan
__global__ void __launch_bounds__(256) brankfind_kernel(
    const u32* rec, const u32* tb, const u32* lrarr, const u32* fbase,
    const u32* cnt, const uint2* keytab, u32* Tbuf, u32* idx, Batch bt) {
  __shared__ u64 kk[4][CAP];
  __shared__ u32 bins[4][64];
  __shared__ u32 cand[4][64];
  __shared__ u32 ncand_s[4];
  const Item P = bt.it[blockIdx.y];
  int w = threadIdx.x >> 6;
  int lane = threadIdx.x & 63;
  int r = blockIdx.x * 4 + w;
  u32 gb = tb[P.t_off + r];
  u32 lr = lrarr[P.t_off + r];
  int img = (gb >= (u32)P.NB) ? 1 : 0;
  uint2 sk = keytab[P.sub_base + img * 3];
  u32 s0 = P.rec_off + (u32)img * (P.rec_cap >> 1) + fbase[P.cnt_off + gb];
  u32 m = cnt[P.cnt_off + gb];
  if (m > CAP) m = CAP;
  int shamt = 26 - P.BB;
  bins[w][lane] = 0u;
  if (lane == 0) ncand_s[w] = 0u;
  for (u32 i = lane; i < m; i += 64) {
    u32 q = rec[s0 + i];
    kk[w][i] = ((u64)sortbits(sk, q, P.n) << 32) | (u64)q;
  }
  __syncthreads();
  for (u32 i = lane; i < m; i += 64)
    atomicAdd(&bins[w][((u32)(kk[w][i] >> 32) >> shamt) & 63u], 1u);
  __syncthreads();
  u32 own = bins[w][lane];
  u32 incl = own;
  #pragma unroll
  for (int d = 1; d < 64; d <<= 1) {
    u32 v = __shfl_up(incl, d, 64);
    if (lane >= d) incl += v;
  }
  u32 excl = incl - own;
  u64 mask = __ballot(excl <= lr && lr < incl);
  int sb = __ffsll((long long)mask) - 1;
  u32 sexcl = __shfl(excl, sb, 64);
  u32 lr2 = lr - sexcl;
  for (u32 i = lane; i < m; i += 64) {
    if ((((u32)(kk[w][i] >> 32) >> shamt) & 63u) == (u32)sb) {
      u32 pos = atomicAdd(&ncand_s[w], 1u);
      if (pos < 64u) cand[w][pos] = i;
    }
  }
  __syncthreads();
  u32 nc = ncand_s[w];
  if (nc > 64u) nc = 64u;
  u32* outp = P.out_is_idx ? (idx + P.out_off) : (Tbuf + P.t_off);
  if ((u32)lane < nc) {
    u64 me = kk[w][cand[w][lane]];
    u32 c = 0;
    for (u32 j = 0; j < nc; j++) c += (kk[w][cand[w][j]] < me) ? 1u : 0u;
    if (c == lr2) outp[r] = (u32)(me & 0xffffffffu);
  }
}

// gather sampled pixels (bilinear align_corners from 2048x2048 source)
__global__ void gather_kernel(const float* wimg, const float* timg,
                              const u32* idx, float* pix) {
  int t = blockIdx.x * blockDim.x + threadIdx.x;
  if (t >= 65536) return;
  int j = t & 4095;
  int img = (t >> 12) & 1;
  int l = t >> 13;
  int s = 16 << l;
  long long n = (long long)s * s;
  int M = (n < 4096) ? (int)n : 4096;
  if (j >= M) return;
  u32 p = (l < 3) ? (u32)j : idx[((l - 3) * 2 + img) * 4096 + j];
  const float* src = img ? timg : wimg;
  float o0, o1, o2;
  if (l == 7) {
    o0 = src[p];
    o1 = src[4194304 + p];
    o2 = src[8388608 + p];
  } else {
    u32 y = p / (u32)s, xq = p % (u32)s;
    float delta = 2047.0f / (float)(s - 1);
    float yc = (float)y * delta, xc = (float)xq * delta;
    int y0 = (int)floorf(yc); if (y0 > 2047) y0 = 2047;
    int x0 = (int)floorf(xc); if (x0 > 2047) x0 = 2047;
    int y1 = y0 + 1; if (y1 > 2047) y1 = 2047;
    int x1 = x0 + 1; if (x1 > 2047) x1 = 2047;
    float wy = yc - (float)y0, wx = xc - (float)x0;
    float out3[3];
    for (int c = 0; c < 3; c++) {
      const float* b = src + (size_t)c * 4194304;
      float v00 = b[y0 * 2048 + x0], v01 = b[y0 * 2048 + x1];
      float v10 = b[y1 * 2048 + x0], v11 = b[y1 * 2048 + x1];
      float r0 = v00 * (1.0f - wy) + v10 * wy;
      float r1 = v01 * (1.0f - wy) + v11 * wy;
      out3[c] = r0 * (1.0f - wx) + r1 * wx;
    }
    o0 = out3[0]; o1 = out3[1]; o2 = out3[2];
  }
  float* dst = pix + ((size_t)(l * 2 + img) * 4096 + j) * 3;
  dst[0] = o0; dst[1] = o1; dst[2] = o2;
}

// one block per (level, direction): shfl-bitonic sort of S=M elements.
__global__ void __launch_bounds__(1024) swd_kernel(
    const float* pix, const float* dirs, double* partials) {
  __shared__ float sw[PIDX(4096)];
  __shared__ float st[PIDX(4096)];
  __shared__ double wred[16];
  int b = blockIdx.x;
  int l = b >> 6, k = b & 63;
  int sdim = 16 << l;
  long long nn = (long long)sdim * sdim;
  u32 S = (nn < 4096) ? (u32)nn : 4096u;
  int tid = threadIdx.x;  // 1024
  int half = tid >> 9, t = tid & 511;
  u32 tpa = S >> 3;
  bool act = (u32)t < tpa;
  float d0 = dirs[l * 192 + k * 3 + 0];
  float d1 = dirs[l * 192 + k * 3 + 1];
  float d2 = dirs[l * 192 + k * 3 + 2];
  float* A = half ? st : sw;
  const float* P = pix + (size_t)(l * 2 + half) * 4096 * 3;
  float v[8];
  if (act) {
    const float* q = P + (size_t)t * 24;
    #pragma unroll
    for (int a = 0; a < 8; a++)
      v[a] = q[a * 3] * d0 + q[a * 3 + 1] * d1 + q[a * 3 + 2] * d2;
  }
#define CEV(x, y, up) { if ((v[x] > v[y]) == (up)) { float tt = v[x]; v[x] = v[y]; v[y] = tt; } }
  if (act) {
    CEV(0, 1, true) CEV(2, 3, false) CEV(4, 5, true) CEV(6, 7, false)
    CEV(0, 2, true) CEV(1, 3, true) CEV(4, 6, false) CEV(5, 7, false)
    CEV(0, 1, true) CEV(2, 3, true) CEV(4, 5, false) CEV(6, 7, false)
    {
      bool up8 = ((t & 1) == 0);
      CEV(0, 4, up8) CEV(1, 5, up8) CEV(2, 6, up8) CEV(3, 7, up8)
      CEV(0, 2, up8) CEV(1, 3, up8) CEV(4, 6, up8) CEV(5, 7, up8)
      CEV(0, 1, up8) CEV(2, 3, up8) CEV(4, 5, up8) CEV(6, 7, up8)
    }
  }
  for (u32 k2 = 16; k2 <= S; k2 <<= 1) {
    u32 j = k2 >> 1;
    if (j >= 512) {
      if (act) {
        #pragma unroll
        for (int a = 0; a < 8; a++) A[PIDX(t * 8 + a)] = v[a];
      }
      __syncthreads();
      for (; j >= 512; j >>= 1) {
        if (act) {
          for (u32 p = (u32)t; p < (S >> 1); p += tpa) {
            u32 i = ((p & ~(j - 1)) << 1) | (p & (j - 1));
            u32 ix = i | j;
            bool up = ((i & k2) == 0);
            float a0 = A[PIDX(i)], c0 = A[PIDX(ix)];
            if ((a0 > c0) == up) { A[PIDX(i)] = c0; A[PIDX(ix)] = a0; }
          }
        }
        __syncthreads();
      }
      if (act) {
        #pragma unroll
        for (int a = 0; a < 8; a++) v[a] = A[PIDX(t * 8 + a)];
      }
    }
    bool up = ((((u32)t << 3) & k2) == 0);
    for (; j >= 8; j >>= 1) {
      u32 m = j >> 3;
      if (act) {
        bool lower = ((t & (int)m) == 0);
        #pragma unroll
        for (int a = 0; a < 8; a++) {
          float o = bfly(v[a], m);
          v[a] = (lower == up) ? fminf(v[a], o) : fmaxf(v[a], o);
        }
      }
    }
    if (act) {
      CEV(0, 4, up) CEV(1, 5, up) CEV(2, 6, up) CEV(3, 7, up)
      CEV(0, 2, up) CEV(1, 3, up) CEV(4, 6, up) CEV(5, 7, up)
      CEV(0, 1, up) CEV(2, 3, up) CEV(4, 5, up) CEV(6, 7, up)
    }
  }
#undef CEV
  __syncthreads();
  if (act && half == 1) {
    #pragma unroll
    for (int a = 0; a < 8; a++) st[PIDX(t * 8 + a)] = v[a];
  }
  __syncthreads();
  double sum = 0.0;
  if (act && half == 0) {
    #pragma unroll
    for (int a = 0; a < 8; a++) {
      double df = (double)v[a] - (double)st[PIDX(t * 8 + a)];
      sum += df * df;
    }
  }
  for (int off = 32; off >= 1; off >>= 1) sum += __shfl_down(sum, off);
  if ((tid & 63) == 0) wred[tid >> 6] = sum;
  __syncthreads();
  if (tid == 0) {
    double s2 = 0.0;
    for (int i = 0; i < 16; i++) s2 += wred[i];
    partials[b] = s2;
  }
}

__global__ void final_kernel(const double* partials, float* out) {
  if (threadIdx.x == 0 && blockIdx.x == 0) {
    double tot = 0.0;
    for (int l = 0; l < 8; l++) {
      int s = 16 << l;
      long long nn = (long long)s * s;
      int M = (nn < 4096) ? (int)nn : 4096;
      double sm = 0.0;
      for (int k = 0; k < 64; k++) sm += partials[l * 64 + k];
      tot += sm / (64.0 * (double)M);
    }
    out[0] = (float)tot;
  }
}

// ---------------- launch -----------------------------------------------------
extern "C" void kernel_launch(void* const* d_in, const int* in_sizes, int n_in,
                              void* d_out, int out_size, void* d_ws, size_t ws_size,
                              hipStream_t stream) {
  const float* wimg = (const float*)d_in[0];
  const float* timg = (const float*)d_in[1];
  float* out = (float*)d_out;
  char* ws = (char*)d_ws;

  // per-level static tables (lev 0..4 = pyramid levels 3..7)
  static const u32 Ln[5]    = {16384u, 65536u, 262144u, 1048576u, 4194304u};
  static const int LBB[5]   = {7, 9, 11, 13, 14};
  static const int LNB[5]   = {128, 512, 2048, 8192, 16384};
  static const int Lnblk[5] = {8, 16, 32, 64, 256};
  static const u32 Lhm[5]   = {0u, 2048u, 18432u, 149504u, 1198080u};    // u16 elems
  static const u32 Lgs[5]   = {0u, 256u, 1280u, 9472u, 75008u};         // u32 elems
  static const u32 Lbid[5]  = {0u, 32768u, 163840u, 688128u, 2785280u}; // u16 elems
  static const u32 Lcnt[5]  = {0u, 256u, 1280u, 5376u, 21760u};          // u32 elems
  static const u32 Lrec[5]  = {0u, 32768u, 163840u, 688128u, 1998848u};  // u32 elems
  static const u32 Lcap[5]  = {32768u, 131072u, 524288u, 1310720u, 2621440u};
  const u32 HM_TOTAL = 9586688u;   // Σ nblk*NB2 (L7 at 256 chunks)
  const u32 GS_TOTAL = 599296u;    // Σ ngroups*NB2
  const u32 BID_TOTAL = 11173888u; // Σ 2*n
  const u32 CNT_TOTAL = 54528u;    // Σ NB2
  const u32 REC_TOTAL = 4620288u;  // Σ caps

  size_t off = 0;
  auto alloc = [&](size_t bytes) -> void* {
    void* p = ws + off;
    off = (off + bytes + 255) & ~(size_t)255;
    return p;
  };
  u32* rec     = (u32*)alloc((size_t)REC_TOTAL * 4);   // 18.5 MB
  u16* histmat = (u16*)alloc((size_t)HM_TOTAL * 2);    // 19.2 MB
  u16* offT    = (u16*)alloc((size_t)HM_TOTAL * 2);    // 19.2 MB
  u16* barr    = (u16*)alloc((size_t)BID_TOTAL * 2);   // 22.3 MB
  u32* gsum    = (u32*)alloc((size_t)GS_TOTAL * 4);    // 2.4 MB
  u32* cnt     = (u32*)alloc((size_t)CNT_TOTAL * 4);
  u32* fbase   = (u32*)alloc((size_t)CNT_TOTAL * 4);
  uint2* keyt  = (uint2*)alloc(64 * 8);
  u32* T       = (u32*)alloc(5ull * 8192 * 4);
  u32* tb      = (u32*)alloc(5ull * 8192 * 4);
  u32* lrarr   = (u32*)alloc(5ull * 8192 * 4);
  u32* idx     = (u32*)alloc(5ull * 8192 * 4);
  float* pix   = (float*)alloc(8ull * 2 * 4096 * 3 * 4);
  float* dirs  = (float*)alloc(8ull * 64 * 3 * 4);
  double* part = (double*)alloc(512 * 8);
  (void)ws_size; (void)in_sizes; (void)n_in; (void)out_size;

  hipLaunchKernelGGL(setup_kernel, dim3(1), dim3(512), 0, stream, keyt, dirs);

  // 3 super-rounds
  for (int sr = 0; sr < 3; sr++) {
    Batch bt;
    int m = 0;
    u32 bs = 0, cs = 0;
    u32 maxg = 1;
    for (int lev = 0; lev < 5; lev++) {
      int R = (lev == 4) ? 3 : 2;
      int jr = R - sr;
      if (jr < 1) continue;
      Item& I = bt.it[m++];
      I.n = Ln[lev]; I.chunk = Ln[lev] / (u32)Lnblk[lev];
      I.BB = LBB[lev]; I.NB = LNB[lev]; I.nblk = Lnblk[lev];
      I.hm_off = Lhm[lev]; I.gs_off = Lgs[lev]; I.bid_off = Lbid[lev];
      I.cnt_off = Lcnt[lev];
      I.rec_off = Lrec[lev]; I.rec_cap = Lcap[lev];
      I.blk_start = bs; bs += (u32)Lnblk[lev];
      I.col_start = cs; cs += (u32)((2 * LNB[lev] + 255) / 256);
      u32 ng = (u32)((Lnblk[lev] + GRP - 1) / GRP);
      if (ng > maxg) maxg = ng;
      I.sub_base = 8 + lev * 6 + (jr - 1);
      I.first = (jr == R) ? 1 : 0;
      I.out_is_idx = (jr == 1) ? 1 : 0;
      I.t_off = (u32)lev * 8192u;
      I.out_off = (u32)lev * 8192u;
    }
    bt.nitems = m;
    hipLaunchKernelGGL(bhist_kernel, dim3(bs, 2), dim3(1024), 0, stream,
                       histmat, barr, keyt, bt);
    hipLaunchKernelGGL(bcolscan1_kernel, dim3(cs, maxg), dim3(256), 0, stream,
                       histmat, offT, gsum, bt);
    hipLaunchKernelGGL(bcolscan2_kernel, dim3(cs), dim3(256), 0, stream,
                       gsum, cnt, bt);
    hipLaunchKernelGGL(bplan_kernel, dim3(m, 2), dim3(1024), 0, stream,
                       cnt, fbase, T, tb, lrarr, bt);
    hipLaunchKernelGGL(bscatter_kernel, dim3(bs, 2), dim3(1024), 0, stream,
                       rec, offT, gsum, fbase, barr, bt);
    hipLaunchKernelGGL(brankfind_kernel, dim3(2048, m), dim3(256), 0, stream,
                       rec, tb, lrarr, fbase, cnt, keyt, T, idx, bt);
  }

  hipLaunchKernelGGL(gather_kernel, dim3(256), dim3(256), 0, stream,
                     wimg, timg, idx, pix);
  hipLaunchKernelGGL(swd_kernel, dim3(512), dim3(1024), 0, stream,
                     pix, dirs, part);
  hipLaunchKernelGGL(final_kernel, dim3(1), dim3(1), 0, stream, part, out);
}

// Round 19
// 451.335 us; speedup vs baseline: 1.0626x; 1.0626x over previous
//
#include <hip/hip_runtime.h>
#include <stdint.h>

// ============================================================================
// DistributionLoss: SWD pyramid loss, exact JAX-RNG replication.
// Round 19: revert to round-17 configuration (best: 452us). Round 18's DPP
// butterfly regressed swd 50->78us (branch broke pipelining; bank conflicts
// were from PIDX LDS arrays, not shuffles).
// ============================================================================
#define JAX_PARTITIONABLE 1

typedef unsigned int u32;
typedef unsigned short u16;
typedef unsigned long long u64;

#define CAP     512         // max bucket entries in rankfind
#define MAXNB   16384       // max buckets per image (64KB LDS)
#define GRP     16          // hist rows per colscan group
#define SIDX(i) ((i) + ((i) >> 5))   // LDS pad map: +1 word per 32
#define PIDX(i) ((i) + ((i) >> 3))   // swd pad map: +1 word per 8

// ---------------- threefry2x32 (20 rounds), matches jax exactly -------------
__device__ __forceinline__ uint2 tf2(uint2 k, u32 x0, u32 x1) {
  u32 ks0 = k.x, ks1 = k.y, ks2 = k.x ^ k.y ^ 0x1BD11BDAu;
  x0 += ks0; x1 += ks1;
#define TF_RND(R) { x0 += x1; x1 = (x1 << (R)) | (x1 >> (32 - (R))); x1 ^= x0; }
  TF_RND(13) TF_RND(15) TF_RND(26) TF_RND(6)
  x0 += ks1; x1 += ks2 + 1u;
  TF_RND(17) TF_RND(29) TF_RND(16) TF_RND(24)
  x0 += ks2; x1 += ks0 + 2u;
  TF_RND(13) TF_RND(15) TF_RND(26) TF_RND(6)
  x0 += ks0; x1 += ks1 + 3u;
  TF_RND(17) TF_RND(29) TF_RND(16) TF_RND(24)
  x0 += ks1; x1 += ks2 + 4u;
  TF_RND(13) TF_RND(15) TF_RND(26) TF_RND(6)
  x0 += ks2; x1 += ks0 + 5u;
#undef TF_RND
  return make_uint2(x0, x1);
}

__device__ inline void split3(uint2 k, uint2* a, uint2* b, uint2* c) {
#if JAX_PARTITIONABLE
  *a = tf2(k, 0u, 0u); *b = tf2(k, 0u, 1u); *c = tf2(k, 0u, 2u);
#else
  uint2 p0 = tf2(k, 0u, 3u), p1 = tf2(k, 1u, 4u), p2 = tf2(k, 2u, 5u);
  *a = make_uint2(p0.x, p1.x); *b = make_uint2(p2.x, p0.y); *c = make_uint2(p1.y, p2.y);
#endif
}
__device__ inline void split2(uint2 k, uint2* nk, uint2* sub) {
#if JAX_PARTITIONABLE
  *nk = tf2(k, 0u, 0u); *sub = tf2(k, 0u, 1u);
#else
  uint2 p0 = tf2(k, 0u, 2u), p1 = tf2(k, 1u, 3u);
  *nk = make_uint2(p0.x, p1.x); *sub = make_uint2(p0.y, p1.y);
#endif
}
__device__ inline u32 normbits(uint2 kd, u32 idx) {
#if JAX_PARTITIONABLE
  uint2 o = tf2(kd, 0u, idx); return o.x ^ o.y;
#else
  if (idx < 96u) return tf2(kd, idx, idx + 96u).x;
  return tf2(kd, idx - 96u, idx).y;
#endif
}
__device__ inline u32 sortbits(uint2 sk, u32 p, u32 n) {
#if JAX_PARTITIONABLE
  uint2 o = tf2(sk, 0u, p); return o.x ^ o.y;
#else
  u32 h = n >> 1;
  if (p < h) return tf2(sk, p, p + h).x;
  return tf2(sk, p - h, p).y;
#endif
}

// ---------------- erfinv ----------------------------------------------------
__device__ inline double erfinv_d(double x) {
  double w = -log1p(-x * x);
  double p;
  if (w < 5.0) {
    w -= 2.5;
    p = 2.81022636e-08;
    p = 3.43273939e-07 + p * w;
    p = -3.5233877e-06 + p * w;
    p = -4.39150654e-06 + p * w;
    p = 0.00021858087 + p * w;
    p = -0.00125372503 + p * w;
    p = -0.00417768164 + p * w;
    p = 0.246640727 + p * w;
    p = 1.50140941 + p * w;
  } else {
    w = sqrt(w) - 3.0;
    p = -0.000200214257;
    p = 0.000100950558 + p * w;
    p = 0.00134934322 + p * w;
    p = -0.00367342844 + p * w;
    p = 0.00573950773 + p * w;
    p = -0.0076224613 + p * w;
    p = 0.00943887047 + p * w;
    p = 1.00167406 + p * w;
    p = 2.83297682 + p * w;
  }
  double y = p * x;
  for (int it = 0; it < 2; ++it) {
    double e = erf(y) - x;
    y -= e * 0.88622692545275801364 * exp(y * y);
  }
  return y;
}

// ---------------- batched pipeline descriptors ------------------------------
struct Item {
  u32 n, chunk;
  int BB, NB, nblk;
  u32 hm_off;     // u16-element offset into histmat/offT
  u32 gs_off;     // u32-element offset into gsum
  u32 bid_off;    // u16-element offset into barr (bucket-id cache)
  u32 cnt_off;    // u32-element offset into cnt/fbase
  u32 rec_off;    // u32-element offset into rec
  u32 rec_cap;    // total cap (both images); per-image = cap>>1
  u32 blk_start;  // bhist/bscatter grid.x prefix (fine blocks)
  u32 col_start;  // colscan grid.x prefix
  int sub_base;   // keytab index: 8 + lev*6 + (jr-1); +img*3 at runtime
  int first;      // targets are ranks 0..4095 (first round)
  int out_is_idx; // final round -> write idx, else write T
  u32 t_off;      // per-level offset into T/tb/lrarr (lev*8192)
  u32 out_off;    // per-level offset into idx (lev*8192)
};
struct Batch { int nitems; Item it[5]; };

__device__ inline int find_item_blk(const Batch& bt, u32 bx) {
  int it = 0;
  for (int i = 1; i < bt.nitems; i++) if (bx >= bt.it[i].blk_start) it = i;
  return it;
}
__device__ inline int find_item_col(const Batch& bt, u32 bx) {
  int it = 0;
  for (int i = 1; i < bt.nitems; i++) if (bx >= bt.it[i].col_start) it = i;
  return it;
}

// ---------------- kernels ---------------------------------------------------

// keytab: [0..7] kd per level; [8 + lev*6 + img*3 + (r-1)] sort subkeys.
__global__ void __launch_bounds__(512) setup_kernel(uint2* keytab, float* dirs) {
  __shared__ uint2 kt[64];
  if (threadIdx.x == 0) {
    uint2 base = make_uint2(0u, 42u);
    for (int l = 0; l < 8; l++) {
      uint2 kl = tf2(base, 0u, (u32)l);
      uint2 kd, kw, kt3;
      split3(kl, &kd, &kw, &kt3);
      kt[l] = kd;
      if (l >= 3) {
        for (int img = 0; img < 2; img++) {
          uint2 kp = img ? kt3 : kw;
          for (int r = 0; r < 3; r++) {
            uint2 nk, sub;
            split2(kp, &nk, &sub);
            kt[8 + (l - 3) * 6 + img * 3 + r] = sub;
            kp = nk;
          }
        }
      }
    }
  }
  __syncthreads();
  if (threadIdx.x < 38) keytab[threadIdx.x] = kt[threadIdx.x];
  int t = threadIdx.x;  // 512 = 8 levels * 64 dirs
  int l = t >> 6, k = t & 63;
  uint2 kd = kt[l];
  const float lo = -0.9999999403953552f;
  float dv[3];
  for (int c = 0; c < 3; c++) {
    u32 bits = normbits(kd, (u32)(k * 3 + c));
    float f = __uint_as_float((bits >> 9) | 0x3f800000u) - 1.0f;
    float u = f * 2.0f + lo;
    if (u < lo) u = lo;
    dv[c] = 1.4142135f * (float)erfinv_d((double)u);
  }
  float nrm = sqrtf(dv[0] * dv[0] + dv[1] * dv[1] + dv[2] * dv[2]);
  for (int c = 0; c < 3; c++) dirs[l * 192 + k * 3 + c] = dv[c] / nrm;
}

// per-block LDS histogram; also caches each element's bucket id (u16 barr)
__global__ void __launch_bounds__(1024, 8) bhist_kernel(
    u16* histmat, u16* barr, const uint2* keytab, Batch bt) {
  __shared__ u32 lh[MAXNB];
  int item = find_item_blk(bt, blockIdx.x);
  const Item P = bt.it[item];
  int blk = (int)blockIdx.x - (int)P.blk_start;
  int img = blockIdx.y;
  for (int b = threadIdx.x; b < P.NB; b += 1024) lh[b] = 0u;
  __syncthreads();
  uint2 sk = keytab[P.sub_base + img * 3];
  u16* bidp = barr + P.bid_off + (size_t)img * P.n;
  u32 q0 = (u32)blk * P.chunk, q1 = q0 + P.chunk;
  if (q1 > P.n) q1 = P.n;
  for (u32 q = q0 + threadIdx.x; q < q1; q += 1024) {
    u32 b = sortbits(sk, q, P.n) >> (32 - P.BB);
    bidp[q] = (u16)b;
    atomicAdd(&lh[b], 1u);
  }
  __syncthreads();
  u16* row = histmat + P.hm_off + ((size_t)blk * 2 + img) * P.NB;
  for (int b = threadIdx.x; b < P.NB; b += 1024) row[b] = (u16)lh[b];
}

// colscan level 1: per (bucket-range, group) scan GRP hist rows ->
// group-local offT (u16) + group total gsum (u32). grid (cs, GRP-groups).
__global__ void __launch_bounds__(256) bcolscan1_kernel(
    const u16* histmat, u16* offT, u32* gsum, Batch bt) {
  int item = find_item_col(bt, blockIdx.x);
  const Item P = bt.it[item];
  int NB2 = 2 * P.NB;
  int g = blockIdx.y;
  int ngroups = (P.nblk + GRP - 1) / GRP;
  if (g >= ngroups) return;
  int gb = ((int)blockIdx.x - (int)P.col_start) * 256 + threadIdx.x;
  if (gb >= NB2) return;
  int b0 = g * GRP, b1 = b0 + GRP;
  if (b1 > P.nblk) b1 = P.nblk;
  u32 run = 0;
  for (int blk = b0; blk < b1; blk++) {
    size_t ix = P.hm_off + (size_t)blk * NB2 + gb;
    offT[ix] = (u16)run;
    run += histmat[ix];
  }
  gsum[P.gs_off + (size_t)g * NB2 + gb] = run;
}

// colscan level 2: scan gsum across groups in place (-> group bases);
// emit per-bucket totals cnt. grid (cs).
__global__ void __launch_bounds__(256) bcolscan2_kernel(
    u32* gsum, u32* cnt, Batch bt) {
  int item = find_item_col(bt, blockIdx.x);
  const Item P = bt.it[item];
  int NB2 = 2 * P.NB;
  int ngroups = (P.nblk + GRP - 1) / GRP;
  int gb = ((int)blockIdx.x - (int)P.col_start) * 256 + threadIdx.x;
  if (gb >= NB2) return;
  u32 run = 0;
  for (int g = 0; g < ngroups; g++) {
    size_t ix = P.gs_off + (size_t)g * NB2 + gb;
    u32 c = gsum[ix];
    gsum[ix] = run;
    run += c;
  }
  cnt[P.cnt_off + gb] = run;
}

// one block per (item, image): stage cnt->LDS, rank-scan, locate targets,
// flag buckets (bit31), diff-based compact scan -> fbase (per-image rec half)
__global__ void __launch_bounds__(1024) bplan_kernel(
    const u32* cnt, u32* fbase, const u32* Tbuf, u32* tb, u32* lrarr,
    Batch bt) {
  __shared__ u32 sBase[SIDX(MAXNB)];   // 16896 u32 = 66KB (padded)
  __shared__ u32 wsum[16];
  const u32 MASK = 0x7fffffffu;
  const Item P = bt.it[blockIdx.x];
  int img = blockIdx.y;
  int NB = P.NB;
  u32 n = P.n;
  const u32* cntp = cnt + P.cnt_off + (size_t)img * NB;
  u32* fbp = fbase + P.cnt_off + (size_t)img * NB;
  int tid = threadIdx.x;
  int lane = tid & 63, wid = tid >> 6;
  int chunk = (NB + 1023) >> 10;
  int s = tid * chunk, e = s + chunk;
  if (e > NB) e = NB;
  if (s > NB) s = NB;
  for (int i = tid; i < NB; i += 1024) sBase[SIDX(i)] = cntp[i];
  __syncthreads();
  u32 own = 0;
  for (int i = s; i < e; i++) own += sBase[SIDX(i)];
  u32 incl = own;
  #pragma unroll
  for (int d = 1; d < 64; d <<= 1) {
    u32 v = __shfl_up(incl, d, 64);
    if (lane >= d) incl += v;
  }
  if (lane == 63) wsum[wid] = incl;
  __syncthreads();
  if (wid == 0) {
    u32 wv = (lane < 16) ? wsum[lane] : 0u;
    u32 wi = wv;
    #pragma unroll
    for (int d = 1; d < 16; d <<= 1) {
      u32 v = __shfl_up(wi, d, 64);
      if (lane >= d) wi += v;
    }
    if (lane < 16) wsum[lane] = wi - wv;
  }
  __syncthreads();
  u32 run = wsum[wid] + (incl - own);
  for (int i = s; i < e; i++) {
    u32 c = sBase[SIDX(i)];
    sBase[SIDX(i)] = run;
    run += c;
  }
  __syncthreads();
  for (int rl = tid; rl < 4096; rl += 1024) {
    int rg = img * 4096 + rl;
    u32 t = P.first ? (u32)rl : Tbuf[P.t_off + rg];
    int lo = 0, hi = NB - 1;
    while (lo < hi) {
      int mid = (lo + hi + 1) >> 1;
      if ((sBase[SIDX(mid)] & MASK) <= t) lo = mid; else hi = mid - 1;
    }
    tb[P.t_off + rg] = (u32)(img * NB + lo);
    lrarr[P.t_off + rg] = t - (sBase[SIDX(lo)] & MASK);
    atomicOr(&sBase[SIDX(lo)], 0x80000000u);
  }
  __syncthreads();
  // diff-based compact scan (cnt[i] = A[i+1]-A[i]); img-local fbase
  u32 bvA = (e < NB) ? (sBase[SIDX(e)] & MASK) : n;
  u32 vs = 0;
  for (int i = s; i < e; i++) {
    u32 st = sBase[SIDX(i)];
    u32 Ai = st & MASK;
    u32 Ai1 = (i == e - 1) ? bvA : (sBase[SIDX(i + 1)] & MASK);
    vs += (st >> 31) ? (Ai1 - Ai) : 0u;
  }
  u32 vincl = vs;
  #pragma unroll
  for (int d = 1; d < 64; d <<= 1) {
    u32 v = __shfl_up(vincl, d, 64);
    if (lane >= d) vincl += v;
  }
  if (lane == 63) wsum[wid] = vincl;
  __syncthreads();
  if (wid == 0) {
    u32 wv = (lane < 16) ? wsum[lane] : 0u;
    u32 wi = wv;
    #pragma unroll
    for (int d = 1; d < 16; d <<= 1) {
      u32 v = __shfl_up(wi, d, 64);
      if (lane >= d) wi += v;
    }
    if (lane < 16) wsum[lane] = wi - wv;
  }
  __syncthreads();
  u32 run2 = wsum[wid] + (vincl - vs);
  for (int i = s; i < e; i++) {
    u32 st = sBase[SIDX(i)];
    u32 Ai = st & MASK;
    u32 Ai1 = (i == e - 1) ? bvA : (sBase[SIDX(i + 1)] & MASK);
    u32 ci = Ai1 - Ai;
    if (st >> 31) {
      sBase[SIDX(i)] = run2;
      run2 += ci;
    } else {
      sBase[SIDX(i)] = 0xFFFFFFFFu;
    }
  }
  __syncthreads();
  for (int i = tid; i < NB; i += 1024) fbp[i] = sBase[SIDX(i)];
}

// fine-block scatter (XCD-swizzled) reading cached bucket ids from barr.
__global__ void __launch_bounds__(1024, 8) bscatter_kernel(
    u32* rec, const u16* offT, const u32* gsum, const u32* fbase,
    const u16* barr, Batch bt) {
  __shared__ u32 cursor[MAXNB];
  int item = find_item_blk(bt, blockIdx.x);
  const Item P = bt.it[item];
  int il = (int)blockIdx.x - (int)P.blk_start;
  int per = P.nblk >> 3;                 // nblk divisible by 8
  int blk = (il & 7) * per + (il >> 3);  // XCD il&7 gets contiguous chunks
  int img = blockIdx.y;
  int NB2 = 2 * P.NB;
  u32 recbase = P.rec_off + (u32)img * (P.rec_cap >> 1);
  const u16* orow = offT + P.hm_off + (size_t)blk * NB2 + (size_t)img * P.NB;
  const u32* grow = gsum + P.gs_off + (size_t)(blk / GRP) * NB2 + (size_t)img * P.NB;
  const u32* frow = fbase + P.cnt_off + (size_t)img * P.NB;
  for (int b = threadIdx.x; b < P.NB; b += 1024) {
    u32 fb = frow[b];
    cursor[b] = (fb == 0xFFFFFFFFu) ? 0xFFFFFFFFu
                                    : recbase + fb + grow[b] + orow[b];
  }
  __syncthreads();
  const u16* bidp = barr + P.bid_off + (size_t)img * P.n;
  u32 limit = recbase + (P.rec_cap >> 1);
  u32 q0 = (u32)blk * P.chunk, q1 = q0 + P.chunk;
  if (q1 > P.n) q1 = P.n;
  for (u32 q = q0 + threadIdx.x; q < q1; q += 1024) {
    u32 b = (u32)bidp[q];
    if (cursor[b] != 0xFFFFFFFFu) {
      u32 slot = atomicAdd(&cursor[b], 1u);
      if (slot < limit) rec[slot] = q;
    }
  }
}

// wave-per-target rank find: recompute bits from q; 64-bin sub-radix; shfl scan
__global__ void __launch_bounds__(256) brankfind_kernel(
    const u32* rec, const u32* tb, const u32* lrarr, const u32* fbase,
    const u32* cnt, const uint2* keytab, u32* Tbuf, u32* idx, Batch bt) {
  __shared__ u64 kk[4][CAP];
  __shared__ u32 bins[4][64];
  __shared__ u32 cand[4][64];
  __shared__ u32 ncand_s[4];
  const Item P = bt.it[blockIdx.y];
  int w = threadIdx.x >> 6;
  int lane = threadIdx.x & 63;
  int r = blockIdx.x * 4 + w;
  u32 gb = tb[P.t_off + r];
  u32 lr = lrarr[P.t_off + r];
  int img = (gb >= (u32)P.NB) ? 1 : 0;
  uint2 sk = keytab[P.sub_base + img * 3];
  u32 s0 = P.rec_off + (u32)img * (P.rec_cap >> 1) + fbase[P.cnt_off + gb];
  u32 m = cnt[P.cnt_off + gb];
  if (m > CAP) m = CAP;
  int shamt = 26 - P.BB;
  bins[w][lane] = 0u;
  if (lane == 0) ncand_s[w] = 0u;
  for (u32 i = lane; i < m; i += 64) {
    u32 q = rec[s0 + i];
    kk[w][i] = ((u64)sortbits(sk, q, P.n) << 32) | (u64)q;
  }
  __syncthreads();
  for (u32 i = lane; i < m; i += 64)
    atomicAdd(&bins[w][((u32)(kk[w][i] >> 32) >> shamt) & 63u], 1u);
  __syncthreads();
  u32 own = bins[w][lane];
  u32 incl = own;
  #pragma unroll
  for (int d = 1; d < 64; d <<= 1) {
    u32 v = __shfl_up(incl, d, 64);
    if (lane >= d) incl += v;
  }
  u32 excl = incl - own;
  u64 mask = __ballot(excl <= lr && lr < incl);
  int sb = __ffsll((long long)mask) - 1;
  u32 sexcl = __shfl(excl, sb, 64);
  u32 lr2 = lr - sexcl;
  for (u32 i = lane; i < m; i += 64) {
    if ((((u32)(kk[w][i] >> 32) >> shamt) & 63u) == (u32)sb) {
      u32 pos = atomicAdd(&ncand_s[w], 1u);
      if (pos < 64u) cand[w][pos] = i;
    }
  }
  __syncthreads();
  u32 nc = ncand_s[w];
  if (nc > 64u) nc = 64u;
  u32* outp = P.out_is_idx ? (idx + P.out_off) : (Tbuf + P.t_off);
  if ((u32)lane < nc) {
    u64 me = kk[w][cand[w][lane]];
    u32 c = 0;
    for (u32 j = 0; j < nc; j++) c += (kk[w][cand[w][j]] < me) ? 1u : 0u;
    if (c == lr2) outp[r] = (u32)(me & 0xffffffffu);
  }
}

// gather sampled pixels (bilinear align_corners from 2048x2048 source)
__global__ void gather_kernel(const float* wimg, const float* timg,
                              const u32* idx, float* pix) {
  int t = blockIdx.x * blockDim.x + threadIdx.x;
  if (t >= 65536) return;
  int j = t & 4095;
  int img = (t >> 12) & 1;
  int l = t >> 13;
  int s = 16 << l;
  long long n = (long long)s * s;
  int M = (n < 4096) ? (int)n : 4096;
  if (j >= M) return;
  u32 p = (l < 3) ? (u32)j : idx[((l - 3) * 2 + img) * 4096 + j];
  const float* src = img ? timg : wimg;
  float o0, o1, o2;
  if (l == 7) {
    o0 = src[p];
    o1 = src[4194304 + p];
    o2 = src[8388608 + p];
  } else {
    u32 y = p / (u32)s, xq = p % (u32)s;
    float delta = 2047.0f / (float)(s - 1);
    float yc = (float)y * delta, xc = (float)xq * delta;
    int y0 = (int)floorf(yc); if (y0 > 2047) y0 = 2047;
    int x0 = (int)floorf(xc); if (x0 > 2047) x0 = 2047;
    int y1 = y0 + 1; if (y1 > 2047) y1 = 2047;
    int x1 = x0 + 1; if (x1 > 2047) x1 = 2047;
    float wy = yc - (float)y0, wx = xc - (float)x0;
    float out3[3];
    for (int c = 0; c < 3; c++) {
      const float* b = src + (size_t)c * 4194304;
      float v00 = b[y0 * 2048 + x0], v01 = b[y0 * 2048 + x1];
      float v10 = b[y1 * 2048 + x0], v11 = b[y1 * 2048 + x1];
      float r0 = v00 * (1.0f - wy) + v10 * wy;
      float r1 = v01 * (1.0f - wy) + v11 * wy;
      out3[c] = r0 * (1.0f - wx) + r1 * wx;
    }
    o0 = out3[0]; o1 = out3[1]; o2 = out3[2];
  }
  float* dst = pix + ((size_t)(l * 2 + img) * 4096 + j) * 3;
  dst[0] = o0; dst[1] = o1; dst[2] = o2;
}

// one block per (level, direction): shfl-bitonic sort of S=M elements.
__global__ void __launch_bounds__(1024) swd_kernel(
    const float* pix, const float* dirs, double* partials) {
  __shared__ float sw[PIDX(4096)];
  __shared__ float st[PIDX(4096)];
  __shared__ double wred[16];
  int b = blockIdx.x;
  int l = b >> 6, k = b & 63;
  int sdim = 16 << l;
  long long nn = (long long)sdim * sdim;
  u32 S = (nn < 4096) ? (u32)nn : 4096u;
  int tid = threadIdx.x;  // 1024
  int half = tid >> 9, t = tid & 511;
  u32 tpa = S >> 3;
  bool act = (u32)t < tpa;
  float d0 = dirs[l * 192 + k * 3 + 0];
  float d1 = dirs[l * 192 + k * 3 + 1];
  float d2 = dirs[l * 192 + k * 3 + 2];
  float* A = half ? st : sw;
  const float* P = pix + (size_t)(l * 2 + half) * 4096 * 3;
  float v[8];
  if (act) {
    const float* q = P + (size_t)t * 24;
    #pragma unroll
    for (int a = 0; a < 8; a++)
      v[a] = q[a * 3] * d0 + q[a * 3 + 1] * d1 + q[a * 3 + 2] * d2;
  }
#define CEV(x, y, up) { if ((v[x] > v[y]) == (up)) { float tt = v[x]; v[x] = v[y]; v[y] = tt; } }
  if (act) {
    CEV(0, 1, true) CEV(2, 3, false) CEV(4, 5, true) CEV(6, 7, false)
    CEV(0, 2, true) CEV(1, 3, true) CEV(4, 6, false) CEV(5, 7, false)
    CEV(0, 1, true) CEV(2, 3, true) CEV(4, 5, false) CEV(6, 7, false)
    {
      bool up8 = ((t & 1) == 0);
      CEV(0, 4, up8) CEV(1, 5, up8) CEV(2, 6, up8) CEV(3, 7, up8)
      CEV(0, 2, up8) CEV(1, 3, up8) CEV(4, 6, up8) CEV(5, 7, up8)
      CEV(0, 1, up8) CEV(2, 3, up8) CEV(4, 5, up8) CEV(6, 7, up8)
    }
  }
  for (u32 k2 = 16; k2 <= S; k2 <<= 1) {
    u32 j = k2 >> 1;
    if (j >= 512) {
      if (act) {
        #pragma unroll
        for (int a = 0; a < 8; a++) A[PIDX(t * 8 + a)] = v[a];
      }
      __syncthreads();
      for (; j >= 512; j >>= 1) {
        if (act) {
          for (u32 p = (u32)t; p < (S >> 1); p += tpa) {
            u32 i = ((p & ~(j - 1)) << 1) | (p & (j - 1));
            u32 ix = i | j;
            bool up = ((i & k2) == 0);
            float a0 = A[PIDX(i)], c0 = A[PIDX(ix)];
            if ((a0 > c0) == up) { A[PIDX(i)] = c0; A[PIDX(ix)] = a0; }
          }
        }
        __syncthreads();
      }
      if (act) {
        #pragma unroll
        for (int a = 0; a < 8; a++) v[a] = A[PIDX(t * 8 + a)];
      }
    }
    bool up = ((((u32)t << 3) & k2) == 0);
    for (; j >= 8; j >>= 1) {
      u32 m = j >> 3;
      if (act) {
        bool lower = ((t & (int)m) == 0);
        #pragma unroll
        for (int a = 0; a < 8; a++) {
          float o = __shfl_xor(v[a], (int)m, 64);
          v[a] = (lower == up) ? fminf(v[a], o) : fmaxf(v[a], o);
        }
      }
    }
    if (act) {
      CEV(0, 4, up) CEV(1, 5, up) CEV(2, 6, up) CEV(3, 7, up)
      CEV(0, 2, up) CEV(1, 3, up) CEV(4, 6, up) CEV(5, 7, up)
      CEV(0, 1, up) CEV(2, 3, up) CEV(4, 5, up) CEV(6, 7, up)
    }
  }
#undef CEV
  __syncthreads();
  if (act && half == 1) {
    #pragma unroll
    for (int a = 0; a < 8; a++) st[PIDX(t * 8 + a)] = v[a];
  }
  __syncthreads();
  double sum = 0.0;
  if (act && half == 0) {
    #pragma unroll
    for (int a = 0; a < 8; a++) {
      double df = (double)v[a] - (double)st[PIDX(t * 8 + a)];
      sum += df * df;
    }
  }
  for (int off = 32; off >= 1; off >>= 1) sum += __shfl_down(sum, off);
  if ((tid & 63) == 0) wred[tid >> 6] = sum;
  __syncthreads();
  if (tid == 0) {
    double s2 = 0.0;
    for (int i = 0; i < 16; i++) s2 += wred[i];
    partials[b] = s2;
  }
}

__global__ void final_kernel(const double* partials, float* out) {
  if (threadIdx.x == 0 && blockIdx.x == 0) {
    double tot = 0.0;
    for (int l = 0; l < 8; l++) {
      int s = 16 << l;
      long long nn = (long long)s * s;
      int M = (nn < 4096) ? (int)nn : 4096;
      double sm = 0.0;
      for (int k = 0; k < 64; k++) sm += partials[l * 64 + k];
      tot += sm / (64.0 * (double)M);
    }
    out[0] = (float)tot;
  }
}

// ---------------- launch -----------------------------------------------------
extern "C" void kernel_launch(void* const* d_in, const int* in_sizes, int n_in,
                              void* d_out, int out_size, void* d_ws, size_t ws_size,
                              hipStream_t stream) {
  const float* wimg = (const float*)d_in[0];
  const float* timg = (const float*)d_in[1];
  float* out = (float*)d_out;
  char* ws = (char*)d_ws;

  // per-level static tables (lev 0..4 = pyramid levels 3..7)
  static const u32 Ln[5]    = {16384u, 65536u, 262144u, 1048576u, 4194304u};
  static const int LBB[5]   = {7, 9, 11, 13, 14};
  static const int LNB[5]   = {128, 512, 2048, 8192, 16384};
  static const int Lnblk[5] = {8, 16, 32, 64, 256};
  static const u32 Lhm[5]   = {0u, 2048u, 18432u, 149504u, 1198080u};    // u16 elems
  static const u32 Lgs[5]   = {0u, 256u, 1280u, 9472u, 75008u};         // u32 elems
  static const u32 Lbid[5]  = {0u, 32768u, 163840u, 688128u, 2785280u}; // u16 elems
  static const u32 Lcnt[5]  = {0u, 256u, 1280u, 5376u, 21760u};          // u32 elems
  static const u32 Lrec[5]  = {0u, 32768u, 163840u, 688128u, 1998848u};  // u32 elems
  static const u32 Lcap[5]  = {32768u, 131072u, 524288u, 1310720u, 2621440u};
  const u32 HM_TOTAL = 9586688u;   // Σ nblk*NB2 (L7 at 256 chunks)
  const u32 GS_TOTAL = 599296u;    // Σ ngroups*NB2
  const u32 BID_TOTAL = 11173888u; // Σ 2*n
  const u32 CNT_TOTAL = 54528u;    // Σ NB2
  const u32 REC_TOTAL = 4620288u;  // Σ caps

  size_t off = 0;
  auto alloc = [&](size_t bytes) -> void* {
    void* p = ws + off;
    off = (off + bytes + 255) & ~(size_t)255;
    return p;
  };
  u32* rec     = (u32*)alloc((size_t)REC_TOTAL * 4);   // 18.5 MB
  u16* histmat = (u16*)alloc((size_t)HM_TOTAL * 2);    // 19.2 MB
  u16* offT    = (u16*)alloc((size_t)HM_TOTAL * 2);    // 19.2 MB
  u16* barr    = (u16*)alloc((size_t)BID_TOTAL * 2);   // 22.3 MB
  u32* gsum    = (u32*)alloc((size_t)GS_TOTAL * 4);    // 2.4 MB
  u32* cnt     = (u32*)alloc((size_t)CNT_TOTAL * 4);
  u32* fbase   = (u32*)alloc((size_t)CNT_TOTAL * 4);
  uint2* keyt  = (uint2*)alloc(64 * 8);
  u32* T       = (u32*)alloc(5ull * 8192 * 4);
  u32* tb      = (u32*)alloc(5ull * 8192 * 4);
  u32* lrarr   = (u32*)alloc(5ull * 8192 * 4);
  u32* idx     = (u32*)alloc(5ull * 8192 * 4);
  float* pix   = (float*)alloc(8ull * 2 * 4096 * 3 * 4);
  float* dirs  = (float*)alloc(8ull * 64 * 3 * 4);
  double* part = (double*)alloc(512 * 8);
  (void)ws_size; (void)in_sizes; (void)n_in; (void)out_size;

  hipLaunchKernelGGL(setup_kernel, dim3(1), dim3(512), 0, stream, keyt, dirs);

  // 3 super-rounds
  for (int sr = 0; sr < 3; sr++) {
    Batch bt;
    int m = 0;
    u32 bs = 0, cs = 0;
    u32 maxg = 1;
    for (int lev = 0; lev < 5; lev++) {
      int R = (lev == 4) ? 3 : 2;
      int jr = R - sr;
      if (jr < 1) continue;
      Item& I = bt.it[m++];
      I.n = Ln[lev]; I.chunk = Ln[lev] / (u32)Lnblk[lev];
      I.BB = LBB[lev]; I.NB = LNB[lev]; I.nblk = Lnblk[lev];
      I.hm_off = Lhm[lev]; I.gs_off = Lgs[lev]; I.bid_off = Lbid[lev];
      I.cnt_off = Lcnt[lev];
      I.rec_off = Lrec[lev]; I.rec_cap = Lcap[lev];
      I.blk_start = bs; bs += (u32)Lnblk[lev];
      I.col_start = cs; cs += (u32)((2 * LNB[lev] + 255) / 256);
      u32 ng = (u32)((Lnblk[lev] + GRP - 1) / GRP);
      if (ng > maxg) maxg = ng;
      I.sub_base = 8 + lev * 6 + (jr - 1);
      I.first = (jr == R) ? 1 : 0;
      I.out_is_idx = (jr == 1) ? 1 : 0;
      I.t_off = (u32)lev * 8192u;
      I.out_off = (u32)lev * 8192u;
    }
    bt.nitems = m;
    hipLaunchKernelGGL(bhist_kernel, dim3(bs, 2), dim3(1024), 0, stream,
                       histmat, barr, keyt, bt);
    hipLaunchKernelGGL(bcolscan1_kernel, dim3(cs, maxg), dim3(256), 0, stream,
                       histmat, offT, gsum, bt);
    hipLaunchKernelGGL(bcolscan2_kernel, dim3(cs), dim3(256), 0, stream,
                       gsum, cnt, bt);
    hipLaunchKernelGGL(bplan_kernel, dim3(m, 2), dim3(1024), 0, stream,
                       cnt, fbase, T, tb, lrarr, bt);
    hipLaunchKernelGGL(bscatter_kernel, dim3(bs, 2), dim3(1024), 0, stream,
                       rec, offT, gsum, fbase, barr, bt);
    hipLaunchKernelGGL(brankfind_kernel, dim3(2048, m), dim3(256), 0, stream,
                       rec, tb, lrarr, fbase, cnt, keyt, T, idx, bt);
  }

  hipLaunchKernelGGL(gather_kernel, dim3(256), dim3(256), 0, stream,
                     wimg, timg, idx, pix);
  hipLaunchKernelGGL(swd_kernel, dim3(512), dim3(1024), 0, stream,
                     pix, dirs, part);
  hipLaunchKernelGGL(final_kernel, dim3(1), dim3(1), 0, stream, part, out);
}